// Round 7
// baseline (623.472 us; speedup 1.0000x reference)
//
#include <hip/hip_runtime.h>
#include <hip/hip_bf16.h>
#include <stdint.h>

#define M_TOTAL 16384   // BATCH * SEQ
#define N_TOTAL 4096    // OUT_FEATURES
#define K_TOTAL 4096    // IN_FEATURES

#define BM 256
#define BN 256
#define BK 64
#define NT (K_TOTAL / BK)   // 64 K-steps

typedef __attribute__((ext_vector_type(4))) float f32x4;
typedef __attribute__((ext_vector_type(4))) int   i32x4;
typedef __attribute__((ext_vector_type(8))) short s16x8;
typedef __attribute__((ext_vector_type(4))) short s16x4;

__device__ __forceinline__ unsigned short f32_to_bf16_rne(float f) {
  union { float f; unsigned u; } c; c.f = f;
  unsigned r = (c.u + 0x7fffu + ((c.u >> 16) & 1u)) >> 16;
  return (unsigned short)r;
}

// x fp32 (M,K) -> bf16 (M,K)
__global__ void cvt_x_kernel(const float* __restrict__ x,
                             unsigned short* __restrict__ xb) {
  const int n4 = M_TOTAL * (K_TOTAL / 4);
  int idx = blockIdx.x * blockDim.x + threadIdx.x;
  int stride = gridDim.x * blockDim.x;
  const f32x4* xv = (const f32x4*)x;
  s16x4* ov = (s16x4*)xb;
  for (int i = idx; i < n4; i += stride) {
    f32x4 v = xv[i];
    s16x4 o;
#pragma unroll
    for (int j = 0; j < 4; ++j) o[j] = (short)f32_to_bf16_rne(v[j]);
    ov[i] = o;
  }
}

// packed int4 (one byte per int32 elem) -> bf16 integer values (N, K) row-major.
__global__ void dequant_w_kernel(const int* __restrict__ wq,
                                 unsigned short* __restrict__ wb) {
  const int n = (N_TOTAL * (K_TOTAL / 2)) / 4;
  int idx = blockIdx.x * blockDim.x + threadIdx.x;
  int stride = gridDim.x * blockDim.x;
  const i32x4* wv = (const i32x4*)wq;
  s16x8* ov = (s16x8*)wb;
  for (int i = idx; i < n; i += stride) {
    i32x4 w = wv[i];
    s16x8 o;
#pragma unroll
    for (int j = 0; j < 4; ++j) {
      int b = w[j];
      int lo = ((b & 0xF) ^ 8) - 8;
      int hi = (((b >> 4) & 0xF) ^ 8) - 8;
      union { float f; unsigned u; } cl, ch;
      cl.f = (float)lo; ch.f = (float)hi;
      o[2 * j]     = (short)(cl.u >> 16);
      o[2 * j + 1] = (short)(ch.u >> 16);
    }
    ov[i] = o;
  }
}

#define MFMA16(a, b, c) __builtin_amdgcn_mfma_f32_16x16x32_bf16((a), (b), (c), 0, 0, 0)
#define SCHED0() __builtin_amdgcn_sched_barrier(0)

// 256x256 tile, BK=64, 8 waves (2x4). m201-style 4-phase/K-tile pipeline:
// each phase = {issue ds_reads for the NEXT cluster; barrier; stage; 16 MFMA
// on operands issued one phase earlier (compiler emits exact counted lgkm)}.
// vmcnt(0) landing-gate once per tile at P2; next-tile reads prefetched at P3.
// T2 LDS swizzle; T1 XCD A-ownership; T5 setprio.
__global__ __launch_bounds__(512, 2) void gemm256_kernel(
    const unsigned short* __restrict__ A,   // M x K bf16
    const unsigned short* __restrict__ B,   // N x K bf16 (int values)
    const float* __restrict__ scales,
    const float* __restrict__ bias,
    float* __restrict__ C) {
  // [buf][A=0/B=1][256 rows][64 cols] bf16 = 128 KB total
  __shared__ unsigned short lds[2][2][BM * BK];

  const int t  = threadIdx.x;
  const int l  = t & 63;
  const int w  = t >> 6;        // wave 0..7
  const int wm = w >> 2;        // 0..1 (M half)
  const int wn = w & 3;         // 0..3 (N quarter)
  const int fr = l & 15;
  const int kg = l >> 4;        // 0..3
  const int sx = fr & 7;        // T2 swizzle XOR (row&7 == fr&7 for all frags)

  // T1/L2: each XCD (wg&7) owns an exclusive 8-tile A block, sweeps bn.
  const int wg = blockIdx.x;                        // nwg = 1024
  const int bm = (wg & 7) * 8 + ((wg >> 3) & 7);    // 0..63
  const int bn = wg >> 6;                           // 0..15

  // Staging: linear LDS dest (global_load_lds), pre-swizzled global source.
  const int rr   = t >> 3;                 // 0..63
  const int ssrc = (t & 7) ^ (rr & 7);
  const unsigned short* pa = A + (size_t)(bm * BM + rr) * K_TOTAL + ssrc * 8;
  const unsigned short* pb = B + (size_t)(bn * BN + rr) * K_TOTAL + ssrc * 8;

#define GLL(gp, lp) __builtin_amdgcn_global_load_lds( \
      (const __attribute__((address_space(1))) unsigned int*)(gp), \
      (__attribute__((address_space(3))) unsigned int*)(lp), 16, 0, 0)

  auto stageA = [&](int buf, int kt) {
#pragma unroll
    for (int g = 0; g < 4; ++g)
      GLL(pa + (size_t)g * 64 * K_TOTAL + kt, &lds[buf][0][g * 4096 + t * 8]);
  };
  auto stageB = [&](int buf, int kt) {
#pragma unroll
    for (int g = 0; g < 4; ++g)
      GLL(pb + (size_t)g * 64 * K_TOTAL + kt, &lds[buf][1][g * 4096 + t * 8]);
  };

  f32x4 acc[8][4] = {};

  const int so0 = (kg ^ sx) * 8;         // kh0 slot (swizzled)
  const int so1 = ((4 + kg) ^ sx) * 8;   // kh1 slot
  const int arow = (wm * 128 + fr) * BK;
  const int brow = (wn * 64 + fr) * BK;

  // Prologue: stage tile 0, gate, read tile-0's first chunk (B0p + AL0p).
  stageA(0, 0); stageB(0, 0);
  asm volatile("s_waitcnt vmcnt(0)" ::: "memory");
  SCHED0();
  __builtin_amdgcn_s_barrier();
  SCHED0();

  s16x8 B0p[4], AL0p[4], AH0[4], B1[4], AL1[4], AH1[4];
  {
    const unsigned short* Abp = &lds[0][0][arow];
    const unsigned short* Bbp = &lds[0][1][brow];
#pragma unroll
    for (int n = 0; n < 4; ++n) B0p[n]  = *(const s16x8*)&Bbp[n * 16 * BK + so0];
#pragma unroll
    for (int m = 0; m < 4; ++m) AL0p[m] = *(const s16x8*)&Abp[m * 16 * BK + so0];
  }
  SCHED0();

  for (int t0 = 0; t0 < NT; ++t0) {
    const int cur = t0 & 1, nxt = cur ^ 1;
    const bool hasNext = (t0 + 1 < NT);
    const int ktn = (t0 + 1) * BK;
    const unsigned short* Abp = &lds[cur][0][arow];
    const unsigned short* Bbp = &lds[cur][1][brow];

    // ---------------- P0: issue AH0 | bar | stageA(t+1) | MFMA AL0p x B0p ----
#pragma unroll
    for (int m = 0; m < 4; ++m) AH0[m] = *(const s16x8*)&Abp[(m + 4) * 16 * BK + so0];
    SCHED0();
    __builtin_amdgcn_s_barrier();
    SCHED0();
    if (hasNext) stageA(nxt, ktn);
    SCHED0();
    __builtin_amdgcn_s_setprio(1);
#pragma unroll
    for (int m = 0; m < 4; ++m)
#pragma unroll
      for (int n = 0; n < 4; ++n)
        acc[m][n] = MFMA16(AL0p[m], B0p[n], acc[m][n]);
    __builtin_amdgcn_s_setprio(0);
    SCHED0();

    // ---------------- P1: issue B1+AL1 | bar | stageB(t+1) | MFMA AH0 x B0p --
#pragma unroll
    for (int n = 0; n < 4; ++n) B1[n]  = *(const s16x8*)&Bbp[n * 16 * BK + so1];
#pragma unroll
    for (int m = 0; m < 4; ++m) AL1[m] = *(const s16x8*)&Abp[m * 16 * BK + so1];
    SCHED0();
    __builtin_amdgcn_s_barrier();
    SCHED0();
    if (hasNext) stageB(nxt, ktn);
    SCHED0();
    __builtin_amdgcn_s_setprio(1);
#pragma unroll
    for (int m = 0; m < 4; ++m)
#pragma unroll
      for (int n = 0; n < 4; ++n)
        acc[m + 4][n] = MFMA16(AH0[m], B0p[n], acc[m + 4][n]);
    __builtin_amdgcn_s_setprio(0);
    SCHED0();

    // ---------------- P2: issue AH1 | vmcnt(0) gate | bar | MFMA AL1 x B1 ----
#pragma unroll
    for (int m = 0; m < 4; ++m) AH1[m] = *(const s16x8*)&Abp[(m + 4) * 16 * BK + so1];
    SCHED0();
    asm volatile("s_waitcnt vmcnt(0)" ::: "memory");   // stage(t+1) landed (own slice)
    SCHED0();
    __builtin_amdgcn_s_barrier();                      // G1: buf[nxt] valid for all
    SCHED0();
    __builtin_amdgcn_s_setprio(1);
#pragma unroll
    for (int m = 0; m < 4; ++m)
#pragma unroll
      for (int n = 0; n < 4; ++n)
        acc[m][n] = MFMA16(AL1[m], B1[n], acc[m][n]);
    __builtin_amdgcn_s_setprio(0);
    SCHED0();

    // ---------------- P3: prefetch next tile's B0p+AL0p | bar | MFMA AH1 x B1
    if (hasNext) {
      const unsigned short* AbpN = &lds[nxt][0][arow];
      const unsigned short* BbpN = &lds[nxt][1][brow];
#pragma unroll
      for (int n = 0; n < 4; ++n) B0p[n]  = *(const s16x8*)&BbpN[n * 16 * BK + so0];
#pragma unroll
      for (int m = 0; m < 4; ++m) AL0p[m] = *(const s16x8*)&AbpN[m * 16 * BK + so0];
    }
    SCHED0();
    __builtin_amdgcn_s_barrier();
    SCHED0();
    __builtin_amdgcn_s_setprio(1);
#pragma unroll
    for (int m = 0; m < 4; ++m)
#pragma unroll
      for (int n = 0; n < 4; ++n)
        acc[m + 4][n] = MFMA16(AH1[m], B1[n], acc[m + 4][n]);
    __builtin_amdgcn_s_setprio(0);
    SCHED0();
  }

  // Epilogue: C/D layout col = lane&15, row = (lane>>4)*4 + reg.
  const int row0 = bm * BM + wm * 128 + kg * 4;
  const int col0 = bn * BN + wn * 64 + fr;
#pragma unroll
  for (int n = 0; n < 4; ++n) {
    const int gc = col0 + n * 16;
    const float s  = scales[gc];
    const float bv = bias[gc];
#pragma unroll
    for (int m = 0; m < 8; ++m) {
      const int gr = row0 + m * 16;
#pragma unroll
      for (int r = 0; r < 4; ++r)
        C[(size_t)(gr + r) * N_TOTAL + gc] = acc[m][n][r] * s + bv;
    }
  }
#undef GLL
}

// Fallback if workspace is too small: correct but slow.
__global__ void naive_int4_kernel(const float* __restrict__ x,
                                  const int* __restrict__ wq,
                                  const float* __restrict__ scales,
                                  const float* __restrict__ bias,
                                  float* __restrict__ out) {
  size_t idx = (size_t)blockIdx.x * blockDim.x + threadIdx.x;
  int o = (int)(idx & (N_TOTAL - 1));
  int m = (int)(idx >> 12);
  const float* xr = x + (size_t)m * K_TOTAL;
  const int* wrow = wq + (size_t)o * (K_TOTAL / 2);
  float acc = 0.f;
  for (int j = 0; j < K_TOTAL / 2; ++j) {
    int b = wrow[j];
    int lo = ((b & 0xF) ^ 8) - 8;
    int hi = (((b >> 4) & 0xF) ^ 8) - 8;
    acc += xr[2 * j] * (float)lo + xr[2 * j + 1] * (float)hi;
  }
  out[idx] = acc * scales[o] + bias[o];
}

extern "C" void kernel_launch(void* const* d_in, const int* in_sizes, int n_in,
                              void* d_out, int out_size, void* d_ws, size_t ws_size,
                              hipStream_t stream) {
  const float* x      = (const float*)d_in[0];
  const int*   wq     = (const int*)d_in[1];
  const float* scales = (const float*)d_in[2];
  const float* bias   = (const float*)d_in[3];
  float* out = (float*)d_out;

  const size_t needA = (size_t)M_TOTAL * K_TOTAL * sizeof(unsigned short);  // 128 MB
  const size_t needW = (size_t)N_TOTAL * K_TOTAL * sizeof(unsigned short);  //  32 MB

  if (d_ws != nullptr && ws_size >= needA + needW) {
    unsigned short* Ab = (unsigned short*)d_ws;
    unsigned short* Wb = (unsigned short*)((char*)d_ws + needA);
    cvt_x_kernel<<<2048, 256, 0, stream>>>(x, Ab);
    dequant_w_kernel<<<1024, 256, 0, stream>>>(wq, Wb);
    gemm256_kernel<<<(M_TOTAL / BM) * (N_TOTAL / BN), 512, 0, stream>>>(Ab, Wb, scales, bias, out);
  } else {
    const size_t total = (size_t)M_TOTAL * N_TOTAL;
    naive_int4_kernel<<<(unsigned)(total / 256), 256, 0, stream>>>(x, wq, scales, bias, out);
  }
}

// Round 8
// 341.922 us; speedup vs baseline: 1.8234x; 1.8234x over previous
//
#include <hip/hip_runtime.h>
#include <hip/hip_bf16.h>
#include <stdint.h>

#define M_TOTAL 16384   // BATCH * SEQ
#define N_TOTAL 4096    // OUT_FEATURES
#define K_TOTAL 4096    // IN_FEATURES

#define BM 256
#define BN 256
#define BKI 128                  // int8 K per tile (128 bytes per LDS row)
#define NTI (K_TOTAL / BKI)      // 32 K-steps

typedef __attribute__((ext_vector_type(4))) float f32x4;
typedef __attribute__((ext_vector_type(4))) int   i32x4;
typedef __attribute__((ext_vector_type(2))) int   i32x2;

// ---------- x fp32 (M,K) -> int8 per-row symmetric quant + qrow ----------
__global__ __launch_bounds__(256) void quant_x_kernel(
    const float* __restrict__ x, signed char* __restrict__ xq,
    float* __restrict__ qrow) {
  __shared__ float red[8];
  const int row = blockIdx.x;                      // 16384 rows
  const int tid = threadIdx.x;
  const float* xr = x + (size_t)row * K_TOTAL;
  const f32x4* xv = (const f32x4*)xr;

  f32x4 v[4];
  float mx = 0.f;
#pragma unroll
  for (int j = 0; j < 4; ++j) {
    v[j] = xv[j * 256 + tid];                      // coalesced float4
#pragma unroll
    for (int e = 0; e < 4; ++e) mx = fmaxf(mx, fabsf(v[j][e]));
  }
#pragma unroll
  for (int off = 32; off > 0; off >>= 1) mx = fmaxf(mx, __shfl_xor(mx, off));
  if ((tid & 63) == 0) red[tid >> 6] = mx;
  __syncthreads();
  if (tid == 0) {
    float m2 = fmaxf(fmaxf(red[0], red[1]), fmaxf(red[2], red[3]));
    red[4] = m2;
    qrow[row] = m2 * (1.f / 127.f);
  }
  __syncthreads();
  const float rmax = red[4];
  const float rq = rmax > 0.f ? 127.f / rmax : 0.f;

  int* oq = (int*)(xq + (size_t)row * K_TOTAL);
#pragma unroll
  for (int j = 0; j < 4; ++j) {
    int b0 = (int)rintf(v[j][0] * rq) & 0xff;
    int b1 = (int)rintf(v[j][1] * rq) & 0xff;
    int b2 = (int)rintf(v[j][2] * rq) & 0xff;
    int b3 = (int)rintf(v[j][3] * rq) & 0xff;
    oq[j * 256 + tid] = b0 | (b1 << 8) | (b2 << 16) | (b3 << 24);
  }
}

// ---------- packed int4 (one byte per int32 elem) -> int8 (N,K) ----------
__global__ void dequant_w8_kernel(const int* __restrict__ wq,
                                  signed char* __restrict__ w8) {
  const int n = (N_TOTAL * (K_TOTAL / 2)) / 4;     // i32x4 groups
  int idx = blockIdx.x * blockDim.x + threadIdx.x;
  int stride = gridDim.x * blockDim.x;
  const i32x4* wv = (const i32x4*)wq;
  i32x2* ov = (i32x2*)w8;
  for (int i = idx; i < n; i += stride) {
    i32x4 w = wv[i];
    int words[2];
#pragma unroll
    for (int h = 0; h < 2; ++h) {
      int b0 = w[2 * h], b1 = w[2 * h + 1];
      int lo0 = (((b0 & 0xF) ^ 8) - 8) & 0xff;
      int hi0 = ((((b0 >> 4) & 0xF) ^ 8) - 8) & 0xff;
      int lo1 = (((b1 & 0xF) ^ 8) - 8) & 0xff;
      int hi1 = ((((b1 >> 4) & 0xF) ^ 8) - 8) & 0xff;
      words[h] = lo0 | (hi0 << 8) | (lo1 << 16) | (hi1 << 24);
    }
    i32x2 o; o[0] = words[0]; o[1] = words[1];
    ov[i] = o;
  }
}

#define MFMAI(a, b, c) __builtin_amdgcn_mfma_i32_16x16x64_i8((a), (b), (c), 0, 0, 0)
#define SCHED0() __builtin_amdgcn_sched_barrier(0)

// int8 GEMM: 256x256 tile, BKI=128, 8 waves (2x4), r3-structure schedule
// (best measured): gate vmcnt(8) -> BarA -> split reads w/ counted lgkm ->
// MFMA0 -> lgkm(0) -> BarB -> stage(t+2) -> MFMA1. T2 swizzle (128B rows,
// identical math to bf16 BK=64), T1 XCD A-ownership, T5 setprio.
__global__ __launch_bounds__(512, 2) void gemm256_i8_kernel(
    const signed char* __restrict__ A8,   // M x K int8
    const signed char* __restrict__ B8,   // N x K int8
    const float* __restrict__ qrow,       // per-row x scale
    const float* __restrict__ scales,
    const float* __restrict__ bias,
    float* __restrict__ C) {
  __shared__ signed char lds[2][2][BM * BKI];   // 2*2*32 KB = 128 KB

  const int t  = threadIdx.x;
  const int l  = t & 63;
  const int w  = t >> 6;
  const int wm = w >> 2;        // 0..1
  const int wn = w & 3;         // 0..3
  const int fr = l & 15;
  const int kg = l >> 4;        // 0..3
  const int sx = fr & 7;        // swizzle XOR (row&7 == fr&7 for all frags)

  const int wg = blockIdx.x;                        // nwg = 1024
  const int bm = (wg & 7) * 8 + ((wg >> 3) & 7);    // 0..63
  const int bn = wg >> 6;                           // 0..15

  // Staging: linear LDS dest, pre-swizzled global source (16B slots).
  const int rr   = t >> 3;                 // 0..63
  const int ssrc = (t & 7) ^ (rr & 7);
  const signed char* pa = A8 + (size_t)(bm * BM + rr) * K_TOTAL + ssrc * 16;
  const signed char* pb = B8 + (size_t)(bn * BN + rr) * K_TOTAL + ssrc * 16;

#define GLL(gp, lp) __builtin_amdgcn_global_load_lds( \
      (const __attribute__((address_space(1))) unsigned int*)(gp), \
      (__attribute__((address_space(3))) unsigned int*)(lp), 16, 0, 0)

  auto stage = [&](int buf, int kt) {
#pragma unroll
    for (int g = 0; g < 4; ++g)
      GLL(pa + (size_t)g * 64 * K_TOTAL + kt, &lds[buf][0][g * 8192 + t * 16]);
#pragma unroll
    for (int g = 0; g < 4; ++g)
      GLL(pb + (size_t)g * 64 * K_TOTAL + kt, &lds[buf][1][g * 8192 + t * 16]);
  };

  i32x4 acc[8][4] = {};

  stage(0, 0);
  stage(1, BKI);

  const int so0 = (kg ^ sx) * 16;         // kk0 byte slot (swizzled)
  const int so1 = ((4 + kg) ^ sx) * 16;   // kk1 byte slot

  for (int t0 = 0; t0 < NTI; ++t0) {
    if (t0 == NTI - 1) { asm volatile("s_waitcnt vmcnt(0)" ::: "memory"); }
    else               { asm volatile("s_waitcnt vmcnt(8)" ::: "memory"); }
    SCHED0();
    __builtin_amdgcn_s_barrier();                       // BarA: buf[cur] ready
    SCHED0();

    const int cur = t0 & 1;
    const signed char* Abp = &lds[cur][0][(wm * 128 + fr) * BKI];
    const signed char* Bbp = &lds[cur][1][(wn * 64 + fr) * BKI];

    i32x4 b[4][2], alo[4][2], ahi[4][2];
    // G1: all B frags (8) + A-lo (8) = 16 ds_read_b128
#pragma unroll
    for (int kk = 0; kk < 2; ++kk) {
      const int so = kk ? so1 : so0;
#pragma unroll
      for (int n = 0; n < 4; ++n) b[n][kk]   = *(const i32x4*)&Bbp[n * 16 * BKI + so];
#pragma unroll
      for (int m = 0; m < 4; ++m) alo[m][kk] = *(const i32x4*)&Abp[m * 16 * BKI + so];
    }
    SCHED0();
    // G2: A-hi (8) — stays outstanding under MFMA cluster 1
#pragma unroll
    for (int kk = 0; kk < 2; ++kk) {
      const int so = kk ? so1 : so0;
#pragma unroll
      for (int m = 0; m < 4; ++m) ahi[m][kk] = *(const i32x4*)&Abp[(m + 4) * 16 * BKI + so];
    }
    SCHED0();
    asm volatile("s_waitcnt lgkmcnt(8)" ::: "memory");  // G1 complete
    SCHED0();
    __builtin_amdgcn_s_setprio(1);
#pragma unroll
    for (int kk = 0; kk < 2; ++kk)
#pragma unroll
      for (int m = 0; m < 4; ++m)
#pragma unroll
        for (int n = 0; n < 4; ++n)
          acc[m][n] = MFMAI(alo[m][kk], b[n][kk], acc[m][n]);
    __builtin_amdgcn_s_setprio(0);
    SCHED0();
    asm volatile("s_waitcnt lgkmcnt(0)" ::: "memory");  // all reads retired
    SCHED0();
    __builtin_amdgcn_s_barrier();                       // BarB: all done reading
    SCHED0();

    if (t0 + 2 < NTI) stage(cur, (t0 + 2) * BKI);       // overwrite consumed buf

    __builtin_amdgcn_s_setprio(1);
#pragma unroll
    for (int kk = 0; kk < 2; ++kk)
#pragma unroll
      for (int m = 0; m < 4; ++m)
#pragma unroll
        for (int n = 0; n < 4; ++n)
          acc[m + 4][n] = MFMAI(ahi[m][kk], b[n][kk], acc[m + 4][n]);
    __builtin_amdgcn_s_setprio(0);
    SCHED0();
  }

  // Epilogue: C/D layout col = lane&15, row = (lane>>4)*4 + reg (dtype-indep).
  const int row0 = bm * BM + wm * 128 + kg * 4;
  const int col0 = bn * BN + wn * 64 + fr;
  float qv[8][4];
#pragma unroll
  for (int m = 0; m < 8; ++m)
#pragma unroll
    for (int r = 0; r < 4; ++r) qv[m][r] = qrow[row0 + m * 16 + r];
#pragma unroll
  for (int n = 0; n < 4; ++n) {
    const int gc = col0 + n * 16;
    const float s  = scales[gc];
    const float bv = bias[gc];
#pragma unroll
    for (int m = 0; m < 8; ++m) {
      const int gr = row0 + m * 16;
#pragma unroll
      for (int r = 0; r < 4; ++r)
        C[(size_t)(gr + r) * N_TOTAL + gc] = (float)acc[m][n][r] * (qv[m][r] * s) + bv;
    }
  }
#undef GLL
}

// Fallback if workspace is too small: correct but slow.
__global__ void naive_int4_kernel(const float* __restrict__ x,
                                  const int* __restrict__ wq,
                                  const float* __restrict__ scales,
                                  const float* __restrict__ bias,
                                  float* __restrict__ out) {
  size_t idx = (size_t)blockIdx.x * blockDim.x + threadIdx.x;
  int o = (int)(idx & (N_TOTAL - 1));
  int m = (int)(idx >> 12);
  const float* xr = x + (size_t)m * K_TOTAL;
  const int* wrow = wq + (size_t)o * (K_TOTAL / 2);
  float acc = 0.f;
  for (int j = 0; j < K_TOTAL / 2; ++j) {
    int b = wrow[j];
    int lo = ((b & 0xF) ^ 8) - 8;
    int hi = (((b >> 4) & 0xF) ^ 8) - 8;
    acc += xr[2 * j] * (float)lo + xr[2 * j + 1] * (float)hi;
  }
  out[idx] = acc * scales[o] + bias[o];
}

extern "C" void kernel_launch(void* const* d_in, const int* in_sizes, int n_in,
                              void* d_out, int out_size, void* d_ws, size_t ws_size,
                              hipStream_t stream) {
  const float* x      = (const float*)d_in[0];
  const int*   wq     = (const int*)d_in[1];
  const float* scales = (const float*)d_in[2];
  const float* bias   = (const float*)d_in[3];
  float* out = (float*)d_out;

  const size_t needXQ = (size_t)M_TOTAL * K_TOTAL;                 // 67.1 MB
  const size_t needW8 = (size_t)N_TOTAL * K_TOTAL;                 // 16.8 MB
  const size_t needQ  = (size_t)M_TOTAL * sizeof(float);           // 64 KB

  if (d_ws != nullptr && ws_size >= needXQ + needW8 + needQ) {
    signed char* xq = (signed char*)d_ws;
    signed char* w8 = (signed char*)d_ws + needXQ;
    float* qrow = (float*)((char*)d_ws + needXQ + needW8);
    quant_x_kernel<<<M_TOTAL, 256, 0, stream>>>(x, xq, qrow);
    dequant_w8_kernel<<<1024, 256, 0, stream>>>(wq, w8);
    gemm256_i8_kernel<<<(M_TOTAL / BM) * (N_TOTAL / BN), 512, 0, stream>>>(
        xq, w8, qrow, scales, bias, out);
  } else {
    const size_t total = (size_t)M_TOTAL * N_TOTAL;
    naive_int4_kernel<<<(unsigned)(total / 256), 256, 0, stream>>>(x, wq, scales, bias, out);
  }
}